// Round 23
// baseline (102.339 us; speedup 1.0000x reference)
//
#include <hip/hip_runtime.h>

typedef unsigned long long u64;
typedef unsigned u32;

#define B_ROWS  262144
#define N_NEG   1310720
#define NBK     512           // buckets = key >> 23
#define CAP     3072          // max bucket size (deterministic counts; verified no-overflow R4-R22)
#define NCHUNK  256
#define EPT     20            // N_NEG / (NCHUNK*256)
#define EPB     3             // CAP/1024 (rank kernels 1024 threads)
#define NBIN    1024          // 10-bit in-bucket counting-sort digit
#define NLB     1024          // loss blocks in k_pos (B_ROWS/256)

// ---------------- ws layout (bytes) ----------------
#define OFF_P1     0u           // NBK*CAP*8 = 12582912 (composite u64)
#define OFF_P2     12582912u    // NBK*CAP*8 = 12582912
#define OFF_STATT  25165824u    // B*8
#define OFF_FB     27262976u    // B*16
#define OFF_POSD   31457280u    // B*4
#define OFF_GC     32505856u    // gcnt1[512]+gcnt2[512] = 4096 (memset node)
#define OFF_SLOTS  32509952u    // 4608 doubles = 36864
#define WS_NEEDED  32546816u

// slot bases (in doubles)
#define SL_POSD  0      // 1024
#define SL_POSCE 1024   // 1024
#define SL_NEGD  2048   // 512
#define SL_NEGCE 2560   // 512
#define SL_NEGN  3072   // 512

struct U2 { unsigned a, b; };

// Threefry-2x32, 20 rounds — matches jax/_src/prng.py threefry2x32.
__host__ __device__ inline U2 tf2x32(unsigned k0, unsigned k1, unsigned c0, unsigned c1) {
  unsigned ks2 = k0 ^ k1 ^ 0x1BD11BDAu;
  unsigned x0 = c0 + k0, x1 = c1 + k1;
#define ROTL(x,d) (((x) << (d)) | ((x) >> (32 - (d))))
#define R4(r0,r1,r2,r3) \
  x0 += x1; x1 = ROTL(x1, r0); x1 ^= x0; \
  x0 += x1; x1 = ROTL(x1, r1); x1 ^= x0; \
  x0 += x1; x1 = ROTL(x1, r2); x1 ^= x0; \
  x0 += x1; x1 = ROTL(x1, r3); x1 ^= x0;
  R4(13,15,26,6)   x0 += k1;  x1 += ks2 + 1u;
  R4(17,29,16,24)  x0 += ks2; x1 += k0  + 2u;
  R4(13,15,26,6)   x0 += k0;  x1 += k1  + 3u;
  R4(17,29,16,24)  x0 += k1;  x1 += ks2 + 4u;
  R4(13,15,26,6)   x0 += ks2; x1 += k0  + 5u;
#undef R4
#undef ROTL
  return U2{x0, x1};
}

__device__ inline u32 keyfn(unsigned k0, unsigned k1, u32 i) {
  U2 c = tf2x32(k0, k1, 0u, i);
  return c.a ^ c.b;
}

// ---------- block reduce over NW waves: thread 0 ends with totals in v[] ----------
template <int N, int NW>
__device__ inline void block_sum(double* v) {
  __shared__ double sh[N][NW];
  int lane = threadIdx.x & 63, w = threadIdx.x >> 6;
#pragma unroll
  for (int j = 0; j < N; ++j) {
    double x = v[j];
    for (int o = 32; o > 0; o >>= 1) x += __shfl_down(x, o);
    if (lane == 0) sh[j][w] = x;
  }
  __syncthreads();
  if (threadIdx.x == 0)
#pragma unroll
    for (int j = 0; j < N; ++j) {
      double s = 0.0;
#pragma unroll
      for (int q = 0; q < NW; ++q) s += sh[j][q];
      v[j] = s;
    }
  __syncthreads();
}

// ---------- exclusive scan across 1024 threads (wave shfl + 16-entry LDS) ----------
__device__ inline u32 scan1024_excl(u32 v, u32* ws, int t) {
  int lane = t & 63, w = t >> 6;   // 16 waves
  u32 incl = v;
#pragma unroll
  for (int o = 1; o < 64; o <<= 1) {
    u32 x = __shfl_up(incl, o);
    if (lane >= o) incl += x;
  }
  if (lane == 63) ws[w] = incl;
  __syncthreads();
  u32 wo = 0;
#pragma unroll
  for (int j = 0; j < 16; ++j) if (j < w) wo += ws[j];
  return wo + incl - v;
}

// ---------------- k_pos: loss blocks [0,1024) + scatter blocks [1024,1280) ----------------
__device__ inline void rowstat(const float* __restrict__ row, int& am, float& conf) {
  float v[10];
  const float2* r2 = (const float2*)row;
#pragma unroll
  for (int j = 0; j < 5; ++j) { float2 x = r2[j]; v[2 * j] = x.x; v[2 * j + 1] = x.y; }
  float m = v[0]; int a = 0;
#pragma unroll
  for (int j = 1; j < 10; ++j) if (v[j] > m) { m = v[j]; a = j; }   // first max, like jnp.argmax
  float s = 0.f;
#pragma unroll
  for (int j = 0; j < 10; ++j) s += expf(v[j] - m);
  am = a;
  conf = 1.0f / s;
}

__global__ __launch_bounds__(256)
void k_pos(const float* __restrict__ et, const float* __restrict__ ef,
           const float* __restrict__ probs,
           const float* __restrict__ pto, const float* __restrict__ pfr,
           u64* __restrict__ statT, float4* __restrict__ FB,
           float* __restrict__ posd, double* __restrict__ sl,
           u64* __restrict__ pairs1, u32* __restrict__ gcnt1,
           u32 k10, u32 k11) {
  __shared__ u32 hh[NBK];
  if (blockIdx.x < NLB) {
    // ---------- loss path ----------
    int i = blockIdx.x * 256 + threadIdx.x;
    int at, af; float ct, cf;
    rowstat(pto + (size_t)i * 10, at, ct);
    rowstat(pfr + (size_t)i * 10, af, cf);
    float2 a = ((const float2*)et)[i];
    float2 b = ((const float2*)ef)[i];
    statT[i] = ((u64)(u32)at << 32) | (u64)__float_as_uint(ct);
    FB[i] = make_float4(b.x, b.y, cf, (float)af);
    float dx = a.x - b.x, dy = a.y - b.y;
    float d = sqrtf(dx * dx + dy * dy);
    posd[i] = (at == af) ? -d : d;          // sign bit encodes is_pred_same
    float pr = probs[i];
    float p  = 1.0f / (1.0f + d * d);
    float pc = fminf(fmaxf(p, 1e-4f), 1.0f);
    float qc = fminf(fmaxf(1.0f - p, 1e-4f), 1.0f);
    float ce = -pr * logf(pc) - (1.0f - pr) * logf(qc);
    double v[2] = {(double)d, (double)ce};
    block_sum<2, 4>(v);
    if (threadIdx.x == 0) {
      sl[SL_POSD + blockIdx.x] = v[0];
      sl[SL_POSCE + blockIdx.x] = v[1];
    }
  } else {
    // ---------- scatter path (concurrent with loss blocks; better CU packing) ----------
    int t = threadIdx.x, ch = blockIdx.x - NLB;
    u32 kv[EPT];
    for (int bq = t; bq < NBK; bq += 256) hh[bq] = 0;
    __syncthreads();
    u32 base = ch * (EPT * 256);
#pragma unroll 4
    for (int e = 0; e < EPT; ++e) {
      kv[e] = keyfn(k10, k11, base + e * 256 + t);
      atomicAdd(&hh[kv[e] >> 23], 1u);
    }
    __syncthreads();
    for (int bq = t; bq < NBK; bq += 256) {
      u32 hv = hh[bq];
      u32 st = hv ? atomicAdd(&gcnt1[bq], hv) : 0u;
      hh[bq] = bq * CAP + st;
    }
    __syncthreads();
#pragma unroll 4
    for (int e = 0; e < EPT; ++e) {
      u32 x = base + e * 256 + t;
      u32 slot = atomicAdd(&hh[kv[e] >> 23], 1u);
      pairs1[slot] = ((u64)(kv[e] & 0x7FFFFFu) << 21) | (u64)x;
    }
  }
}

// ---------------- rank1 (+fused round-2 scatter), 1024 threads, 1024 bins ----------------
// composite1 = (key1low23 << 21) | i ; 10-bit digit = bits [43:34]
__global__ __launch_bounds__(1024)
void k_rank1_scatter2(const u64* __restrict__ pairs1, const u32* __restrict__ gcnt1,
                      u32* __restrict__ gcnt2, u64* __restrict__ pairs2,
                      u32 k20, u32 k21) {
  __shared__ u64 skey[CAP];
  __shared__ u32 binx[NBIN + 1];
  __shared__ u32 bcur[NBIN];
  __shared__ u32 hc[NBK];
  __shared__ u32 ws16[16];
  __shared__ u32 sbase_sh;
  int t = threadIdx.x, b = blockIdx.x;

  // EARLY-ISSUE the 3 pairs loads (unconditional; CAP-sized region, garbage
  // beyond c guarded at use). Latency overlaps the scan prologue.
  u64 kreg[EPB];
#pragma unroll
  for (int q = 0; q < EPB; ++q)
    kreg[q] = pairs1[(size_t)b * CAP + t + q * 1024];

  // base1 = exclusive prefix of gcnt1 (512 entries; threads >=512 contribute 0)
  u32 gv = (t < NBK) ? gcnt1[t] : 0u;
  u32 excl = scan1024_excl(gv, ws16, t);
  if (t == b) sbase_sh = excl;
  binx[t] = 0;
  if (t == 0) binx[NBIN] = 0;
  __syncthreads();
  u32 base1 = sbase_sh;
  u32 c = gcnt1[b]; if (c > CAP) c = CAP;

  // LDS bin histogram (guarded)
#pragma unroll
  for (int q = 0; q < EPB; ++q) {
    int ii = t + q * 1024;
    if (ii < (int)c) atomicAdd(&binx[(u32)(kreg[q] >> 34) & (NBIN - 1)], 1u);
  }
  __syncthreads();
  u32 bv = binx[t];
  u32 bex = scan1024_excl(bv, ws16, t);
  binx[t] = bex; bcur[t] = bex;
  if (t == NBIN - 1) binx[NBIN] = bex + bv;
  __syncthreads();
#pragma unroll
  for (int q = 0; q < EPB; ++q) {
    int ii = t + q * 1024;
    if (ii < (int)c)
      skey[atomicAdd(&bcur[(u32)(kreg[q] >> 34) & (NBIN - 1)], 1u)] = kreg[q];
  }
  __syncthreads();
  // rank -> j ; pack (j<<18)|bb ; cache key2
  u64 jb[EPB]; u32 k2v[EPB];
#pragma unroll
  for (int q = 0; q < EPB; ++q) {
    int s = t + q * 1024;
    if (s < (int)c) {
      u64 k = skey[s];
      u32 d = (u32)(k >> 34) & (NBIN - 1);
      u32 lo = binx[d], hi = binx[d + 1];
      u32 r = lo;
      for (u32 e = lo; e < hi; ++e) r += (skey[e] < k) ? 1u : 0u;
      u32 j = base1 + r;
      u32 i = (u32)k & 0x1FFFFFu;
      jb[q] = ((u64)j << 18) | (u64)(i / 5u);
      k2v[q] = keyfn(k20, k21, j);
    }
  }
  // round-2: hist -> reserve -> scatter packed tuples
  if (t < NBK) hc[t] = 0;
  __syncthreads();
#pragma unroll
  for (int q = 0; q < EPB; ++q) {
    int s = t + q * 1024;
    if (s < (int)c) atomicAdd(&hc[k2v[q] >> 23], 1u);
  }
  __syncthreads();
  if (t < NBK) {
    u32 hv = hc[t];
    u32 st = hv ? atomicAdd(&gcnt2[t], hv) : 0u;
    hc[t] = t * CAP + st;
  }
  __syncthreads();
#pragma unroll
  for (int q = 0; q < EPB; ++q) {
    int s = t + q * 1024;
    if (s < (int)c) {
      u32 slot = atomicAdd(&hc[k2v[q] >> 23], 1u);
      pairs2[slot] = ((u64)(k2v[q] & 0x7FFFFFu) << 39) | jb[q];
    }
  }
}

// ---------------- rank2 + negative loss, 1024 threads, 1024 bins ----------------
// packed = (key2low23 << 39) | (j << 18) | bb ; 10-bit digit = bits [61:52]
__global__ __launch_bounds__(1024)
void k_rank2_loss(const u64* __restrict__ pairs2, const u32* __restrict__ gcnt2,
                  const float* __restrict__ et, const u64* __restrict__ statT,
                  const float4* __restrict__ FB, double* __restrict__ sl) {
  __shared__ u64 skey[CAP];
  __shared__ u32 binx[NBIN + 1];
  __shared__ u32 bcur[NBIN];
  __shared__ u32 ws16[16];
  __shared__ u32 sbase_sh;
  int t = threadIdx.x, b = blockIdx.x;

  // EARLY-ISSUE pairs2 loads
  u64 kreg[EPB];
#pragma unroll
  for (int q = 0; q < EPB; ++q)
    kreg[q] = pairs2[(size_t)b * CAP + t + q * 1024];

  u32 gv = (t < NBK) ? gcnt2[t] : 0u;
  u32 excl = scan1024_excl(gv, ws16, t);
  if (t == b) sbase_sh = excl;
  binx[t] = 0;
  if (t == 0) binx[NBIN] = 0;
  __syncthreads();
  u32 base2 = sbase_sh;
  u32 c = gcnt2[b]; if (c > CAP) c = CAP;

#pragma unroll
  for (int q = 0; q < EPB; ++q) {
    int ii = t + q * 1024;
    if (ii < (int)c) atomicAdd(&binx[(u32)(kreg[q] >> 52) & (NBIN - 1)], 1u);
  }
  __syncthreads();
  u32 bv = binx[t];
  u32 bex = scan1024_excl(bv, ws16, t);
  binx[t] = bex; bcur[t] = bex;
  if (t == NBIN - 1) binx[NBIN] = bex + bv;
  __syncthreads();
#pragma unroll
  for (int q = 0; q < EPB; ++q) {
    int ii = t + q * 1024;
    if (ii < (int)c)
      skey[atomicAdd(&bcur[(u32)(kreg[q] >> 52) & (NBIN - 1)], 1u)] = kreg[q];
  }
  __syncthreads();
  double sd = 0.0, sce = 0.0, sn = 0.0;
#pragma unroll
  for (int q = 0; q < EPB; ++q) {
    int s = t + q * 1024;
    if (s < (int)c) {
      u64 k = skey[s];
      u32 d = (u32)(k >> 52) & (NBIN - 1);
      u32 lo = binx[d], hi = binx[d + 1];
      u32 r = lo;
      for (u32 e = lo; e < hi; ++e) r += (skey[e] < k) ? 1u : 0u;
      u32 p = base2 + r;                  // final permuted position
      u32 bb = (u32)k & 0x3FFFFu;         // from-row (perm-composed)
      u32 a = p / 5u;
      float2 ta = ((const float2*)et)[a];
      float4 fb = FB[bb];
      u64 st = statT[a];
      int at = (int)(st >> 32), af = (int)fb.w;
      float ct = __uint_as_float((u32)st), cf = fb.z;
      float dx = ta.x - fb.x, dy = ta.y - fb.y;
      float dd = sqrtf(dx * dx + dy * dy);
      bool keep = !((af == at) && (cf == ct));
      float pp = 1.0f / (1.0f + dd * dd);
      float qc = fminf(fmaxf(1.0f - pp, 1e-4f), 1.0f);
      float ce = -logf(qc);
      if (keep) { sd += (double)dd; sce += (double)ce; sn += 1.0; }
    }
  }
  double vv[3] = {sd, sce, sn};
  block_sum<3, 16>(vv);
  if (t == 0) {
    sl[SL_NEGD + b] = vv[0];
    sl[SL_NEGCE + b] = vv[1];
    sl[SL_NEGN + b] = vv[2];
  }
}

// ---------------- fused margin + final: 1 block x 1024 threads ----------------
// bm computed ONCE; posd swept via float4 grid-stride within the block.
__global__ __launch_bounds__(1024)
void k_margin_final(const float* __restrict__ posd, const double* __restrict__ sl,
                    float* __restrict__ out) {
  int t = threadIdx.x;
  double v[5];
  v[0] = sl[SL_POSD + t];                              // 1024 entries, 1/thread
  v[1] = sl[SL_POSCE + t];
  v[2] = (t < 512) ? sl[SL_NEGD + t] : 0.0;
  v[3] = (t < 512) ? sl[SL_NEGCE + t] : 0.0;
  v[4] = (t < 512) ? sl[SL_NEGN + t] : 0.0;
  block_sum<5, 16>(v);
  __shared__ float sbm;
  __shared__ float sce_mean;
  if (t == 0) {
    float pm = (float)(v[0] / (double)B_ROWS);
    float nm = (float)(v[2] / v[4]);
    sbm = (pm + nm) * 0.5f;
    sce_mean = (float)((v[1] + v[3]) / ((double)B_ROWS + v[4]));
  }
  __syncthreads();
  float bm = sbm;
  double m = 0.0;
  const float4* p4 = (const float4*)posd;
  for (int i = t; i < B_ROWS / 4; i += 1024) {
    float4 x = p4[i];
    if (!(__float_as_uint(x.x) >> 31)) m += (double)fmaxf(bm - x.x, 0.0f);
    if (!(__float_as_uint(x.y) >> 31)) m += (double)fmaxf(bm - x.y, 0.0f);
    if (!(__float_as_uint(x.z) >> 31)) m += (double)fmaxf(bm - x.z, 0.0f);
    if (!(__float_as_uint(x.w) >> 31)) m += (double)fmaxf(bm - x.w, 0.0f);
  }
  double mm[1] = {m};
  block_sum<1, 16>(mm);
  if (t == 0) {
    float ml = (float)(mm[0] / (double)B_ROWS);
    out[0] = sce_mean + ml;
  }
}

extern "C" void kernel_launch(void* const* d_in, const int* in_sizes, int n_in,
                              void* d_out, int out_size, void* d_ws, size_t ws_size,
                              hipStream_t stream) {
  const float* et  = (const float*)d_in[0];
  const float* ef  = (const float*)d_in[1];
  const float* pr  = (const float*)d_in[2];
  const float* pto = (const float*)d_in[3];
  const float* pfr = (const float*)d_in[4];
  float* out = (float*)d_out;
  if (ws_size < WS_NEEDED) return;   // diagnosable: output stays poisoned

  char* ws = (char*)d_ws;
  u64* pairs1  = (u64*)(ws + OFF_P1);
  u64* pairs2  = (u64*)(ws + OFF_P2);
  u64* statT   = (u64*)(ws + OFF_STATT);
  float4* FB   = (float4*)(ws + OFF_FB);
  float* posd  = (float*)(ws + OFF_POSD);
  u32* gcnt1   = (u32*)(ws + OFF_GC);
  u32* gcnt2   = (u32*)(ws + OFF_GC + NBK * 4);
  double* sl   = (double*)(ws + OFF_SLOTS);

  hipMemsetAsync(ws + OFF_GC, 0, 2 * NBK * 4, stream);

  // Host-side threefry split chain (jax typed key(1) = [0,1]):
  U2 key  = {0u, 1u};
  U2 key1 = tf2x32(key.a, key.b, 0u, 0u);
  U2 sk1  = tf2x32(key.a, key.b, 0u, 1u);
  U2 sk2  = tf2x32(key1.a, key1.b, 0u, 1u);

  k_pos<<<NLB + NCHUNK, 256, 0, stream>>>(et, ef, pr, pto, pfr, statT, FB, posd, sl,
                                          pairs1, gcnt1, sk1.a, sk1.b);
  k_rank1_scatter2<<<NBK, 1024, 0, stream>>>(pairs1, gcnt1, gcnt2, pairs2, sk2.a, sk2.b);
  k_rank2_loss<<<NBK, 1024, 0, stream>>>(pairs2, gcnt2, et, statT, FB, sl);
  k_margin_final<<<1, 1024, 0, stream>>>(posd, sl, out);
}

// Round 24
// 78.334 us; speedup vs baseline: 1.3064x; 1.3064x over previous
//
#include <hip/hip_runtime.h>

typedef unsigned long long u64;
typedef unsigned u32;

#define B_ROWS  262144
#define N_NEG   1310720
#define NBK     512           // buckets = key >> 23
#define CAP     3072          // max bucket size (deterministic counts; verified no-overflow R4-R23)
#define NCHUNK  256
#define EPT     20            // N_NEG / (NCHUNK*256)
#define EPB     3             // CAP/1024 (rank kernels 1024 threads)
#define NBIN    1024          // 10-bit in-bucket counting-sort digit
#define NLB     1024          // loss blocks in k_pos (B_ROWS/256)

// ---------------- ws layout (bytes) ----------------
#define OFF_P1     0u           // NBK*CAP*8 = 12582912 (composite u64)
#define OFF_P2     12582912u    // NBK*CAP*8 = 12582912
#define OFF_STATT  25165824u    // B*8
#define OFF_FB     27262976u    // B*16
#define OFF_POSD   31457280u    // B*4
#define OFF_GC     32505856u    // gcnt1[512]+gcnt2[512] = 4096 (memset node)
#define OFF_SLOTS  32509952u    // 4608 doubles = 36864
#define WS_NEEDED  32546816u

// slot bases (in doubles)
#define SL_POSD  0      // 1024
#define SL_POSCE 1024   // 1024
#define SL_NEGD  2048   // 512
#define SL_NEGCE 2560   // 512
#define SL_NEGN  3072   // 512
#define SL_MAR   3584   // 1024

struct U2 { unsigned a, b; };

// Threefry-2x32, 20 rounds — matches jax/_src/prng.py threefry2x32.
__host__ __device__ inline U2 tf2x32(unsigned k0, unsigned k1, unsigned c0, unsigned c1) {
  unsigned ks2 = k0 ^ k1 ^ 0x1BD11BDAu;
  unsigned x0 = c0 + k0, x1 = c1 + k1;
#define ROTL(x,d) (((x) << (d)) | ((x) >> (32 - (d))))
#define R4(r0,r1,r2,r3) \
  x0 += x1; x1 = ROTL(x1, r0); x1 ^= x0; \
  x0 += x1; x1 = ROTL(x1, r1); x1 ^= x0; \
  x0 += x1; x1 = ROTL(x1, r2); x1 ^= x0; \
  x0 += x1; x1 = ROTL(x1, r3); x1 ^= x0;
  R4(13,15,26,6)   x0 += k1;  x1 += ks2 + 1u;
  R4(17,29,16,24)  x0 += ks2; x1 += k0  + 2u;
  R4(13,15,26,6)   x0 += k0;  x1 += k1  + 3u;
  R4(17,29,16,24)  x0 += k1;  x1 += ks2 + 4u;
  R4(13,15,26,6)   x0 += ks2; x1 += k0  + 5u;
#undef R4
#undef ROTL
  return U2{x0, x1};
}

__device__ inline u32 keyfn(unsigned k0, unsigned k1, u32 i) {
  U2 c = tf2x32(k0, k1, 0u, i);
  return c.a ^ c.b;
}

// ---------- block reduce over NW waves: thread 0 ends with totals in v[] ----------
template <int N, int NW>
__device__ inline void block_sum(double* v) {
  __shared__ double sh[N][NW];
  int lane = threadIdx.x & 63, w = threadIdx.x >> 6;
#pragma unroll
  for (int j = 0; j < N; ++j) {
    double x = v[j];
    for (int o = 32; o > 0; o >>= 1) x += __shfl_down(x, o);
    if (lane == 0) sh[j][w] = x;
  }
  __syncthreads();
  if (threadIdx.x == 0)
#pragma unroll
    for (int j = 0; j < N; ++j) {
      double s = 0.0;
#pragma unroll
      for (int q = 0; q < NW; ++q) s += sh[j][q];
      v[j] = s;
    }
  __syncthreads();
}

// ---------- exclusive scan across 1024 threads (wave shfl + 16-entry LDS) ----------
__device__ inline u32 scan1024_excl(u32 v, u32* ws, int t) {
  int lane = t & 63, w = t >> 6;   // 16 waves
  u32 incl = v;
#pragma unroll
  for (int o = 1; o < 64; o <<= 1) {
    u32 x = __shfl_up(incl, o);
    if (lane >= o) incl += x;
  }
  if (lane == 63) ws[w] = incl;
  __syncthreads();
  u32 wo = 0;
#pragma unroll
  for (int j = 0; j < 16; ++j) if (j < w) wo += ws[j];
  return wo + incl - v;
}

// ---------------- k_pos: loss blocks [0,1024) + scatter blocks [1024,1280) ----------------
__device__ inline void rowstat(const float* __restrict__ row, int& am, float& conf) {
  float v[10];
  const float2* r2 = (const float2*)row;
#pragma unroll
  for (int j = 0; j < 5; ++j) { float2 x = r2[j]; v[2 * j] = x.x; v[2 * j + 1] = x.y; }
  float m = v[0]; int a = 0;
#pragma unroll
  for (int j = 1; j < 10; ++j) if (v[j] > m) { m = v[j]; a = j; }   // first max, like jnp.argmax
  float s = 0.f;
#pragma unroll
  for (int j = 0; j < 10; ++j) s += expf(v[j] - m);
  am = a;
  conf = 1.0f / s;
}

__global__ __launch_bounds__(256)
void k_pos(const float* __restrict__ et, const float* __restrict__ ef,
           const float* __restrict__ probs,
           const float* __restrict__ pto, const float* __restrict__ pfr,
           u64* __restrict__ statT, float4* __restrict__ FB,
           float* __restrict__ posd, double* __restrict__ sl,
           u64* __restrict__ pairs1, u32* __restrict__ gcnt1,
           u32 k10, u32 k11) {
  __shared__ u32 hh[NBK];
  if (blockIdx.x < NLB) {
    // ---------- loss path ----------
    int i = blockIdx.x * 256 + threadIdx.x;
    int at, af; float ct, cf;
    rowstat(pto + (size_t)i * 10, at, ct);
    rowstat(pfr + (size_t)i * 10, af, cf);
    float2 a = ((const float2*)et)[i];
    float2 b = ((const float2*)ef)[i];
    statT[i] = ((u64)(u32)at << 32) | (u64)__float_as_uint(ct);
    FB[i] = make_float4(b.x, b.y, cf, (float)af);
    float dx = a.x - b.x, dy = a.y - b.y;
    float d = sqrtf(dx * dx + dy * dy);
    posd[i] = (at == af) ? -d : d;          // sign bit encodes is_pred_same
    float pr = probs[i];
    float p  = 1.0f / (1.0f + d * d);
    float pc = fminf(fmaxf(p, 1e-4f), 1.0f);
    float qc = fminf(fmaxf(1.0f - p, 1e-4f), 1.0f);
    float ce = -pr * logf(pc) - (1.0f - pr) * logf(qc);
    double v[2] = {(double)d, (double)ce};
    block_sum<2, 4>(v);
    if (threadIdx.x == 0) {
      sl[SL_POSD + blockIdx.x] = v[0];
      sl[SL_POSCE + blockIdx.x] = v[1];
    }
  } else {
    // ---------- scatter path (concurrent with loss blocks; better CU packing) ----------
    int t = threadIdx.x, ch = blockIdx.x - NLB;
    u32 kv[EPT];
    for (int bq = t; bq < NBK; bq += 256) hh[bq] = 0;
    __syncthreads();
    u32 base = ch * (EPT * 256);
#pragma unroll 4
    for (int e = 0; e < EPT; ++e) {
      kv[e] = keyfn(k10, k11, base + e * 256 + t);
      atomicAdd(&hh[kv[e] >> 23], 1u);
    }
    __syncthreads();
    for (int bq = t; bq < NBK; bq += 256) {
      u32 hv = hh[bq];
      u32 st = hv ? atomicAdd(&gcnt1[bq], hv) : 0u;
      hh[bq] = bq * CAP + st;
    }
    __syncthreads();
#pragma unroll 4
    for (int e = 0; e < EPT; ++e) {
      u32 x = base + e * 256 + t;
      u32 slot = atomicAdd(&hh[kv[e] >> 23], 1u);
      pairs1[slot] = ((u64)(kv[e] & 0x7FFFFFu) << 21) | (u64)x;
    }
  }
}

// ---------------- rank1 (+fused round-2 scatter), 1024 threads, 1024 bins ----------------
// composite1 = (key1low23 << 21) | i ; 10-bit digit = bits [43:34]
__global__ __launch_bounds__(1024)
void k_rank1_scatter2(const u64* __restrict__ pairs1, const u32* __restrict__ gcnt1,
                      u32* __restrict__ gcnt2, u64* __restrict__ pairs2,
                      u32 k20, u32 k21) {
  __shared__ u64 skey[CAP];
  __shared__ u32 binx[NBIN + 1];
  __shared__ u32 bcur[NBIN];
  __shared__ u32 hc[NBK];
  __shared__ u32 ws16[16];
  __shared__ u32 sbase_sh;
  int t = threadIdx.x, b = blockIdx.x;

  // EARLY-ISSUE the 3 pairs loads (unconditional; CAP-sized region, garbage
  // beyond c guarded at use). Latency overlaps the scan prologue.
  u64 kreg[EPB];
#pragma unroll
  for (int q = 0; q < EPB; ++q)
    kreg[q] = pairs1[(size_t)b * CAP + t + q * 1024];

  // base1 = exclusive prefix of gcnt1 (512 entries; threads >=512 contribute 0)
  u32 gv = (t < NBK) ? gcnt1[t] : 0u;
  u32 excl = scan1024_excl(gv, ws16, t);
  if (t == b) sbase_sh = excl;
  binx[t] = 0;
  if (t == 0) binx[NBIN] = 0;
  __syncthreads();
  u32 base1 = sbase_sh;
  u32 c = gcnt1[b]; if (c > CAP) c = CAP;

  // LDS bin histogram (guarded)
#pragma unroll
  for (int q = 0; q < EPB; ++q) {
    int ii = t + q * 1024;
    if (ii < (int)c) atomicAdd(&binx[(u32)(kreg[q] >> 34) & (NBIN - 1)], 1u);
  }
  __syncthreads();
  u32 bv = binx[t];
  u32 bex = scan1024_excl(bv, ws16, t);
  binx[t] = bex; bcur[t] = bex;
  if (t == NBIN - 1) binx[NBIN] = bex + bv;
  __syncthreads();
#pragma unroll
  for (int q = 0; q < EPB; ++q) {
    int ii = t + q * 1024;
    if (ii < (int)c)
      skey[atomicAdd(&bcur[(u32)(kreg[q] >> 34) & (NBIN - 1)], 1u)] = kreg[q];
  }
  __syncthreads();
  // rank -> j ; pack (j<<18)|bb ; cache key2
  u64 jb[EPB]; u32 k2v[EPB];
#pragma unroll
  for (int q = 0; q < EPB; ++q) {
    int s = t + q * 1024;
    if (s < (int)c) {
      u64 k = skey[s];
      u32 d = (u32)(k >> 34) & (NBIN - 1);
      u32 lo = binx[d], hi = binx[d + 1];
      u32 r = lo;
      for (u32 e = lo; e < hi; ++e) r += (skey[e] < k) ? 1u : 0u;
      u32 j = base1 + r;
      u32 i = (u32)k & 0x1FFFFFu;
      jb[q] = ((u64)j << 18) | (u64)(i / 5u);
      k2v[q] = keyfn(k20, k21, j);
    }
  }
  // round-2: hist -> reserve -> scatter packed tuples
  if (t < NBK) hc[t] = 0;
  __syncthreads();
#pragma unroll
  for (int q = 0; q < EPB; ++q) {
    int s = t + q * 1024;
    if (s < (int)c) atomicAdd(&hc[k2v[q] >> 23], 1u);
  }
  __syncthreads();
  if (t < NBK) {
    u32 hv = hc[t];
    u32 st = hv ? atomicAdd(&gcnt2[t], hv) : 0u;
    hc[t] = t * CAP + st;
  }
  __syncthreads();
#pragma unroll
  for (int q = 0; q < EPB; ++q) {
    int s = t + q * 1024;
    if (s < (int)c) {
      u32 slot = atomicAdd(&hc[k2v[q] >> 23], 1u);
      pairs2[slot] = ((u64)(k2v[q] & 0x7FFFFFu) << 39) | jb[q];
    }
  }
}

// ---------------- rank2 + negative loss, 1024 threads, 1024 bins ----------------
// packed = (key2low23 << 39) | (j << 18) | bb ; 10-bit digit = bits [61:52]
__global__ __launch_bounds__(1024)
void k_rank2_loss(const u64* __restrict__ pairs2, const u32* __restrict__ gcnt2,
                  const float* __restrict__ et, const u64* __restrict__ statT,
                  const float4* __restrict__ FB, double* __restrict__ sl) {
  __shared__ u64 skey[CAP];
  __shared__ u32 binx[NBIN + 1];
  __shared__ u32 bcur[NBIN];
  __shared__ u32 ws16[16];
  __shared__ u32 sbase_sh;
  int t = threadIdx.x, b = blockIdx.x;

  // EARLY-ISSUE pairs2 loads
  u64 kreg[EPB];
#pragma unroll
  for (int q = 0; q < EPB; ++q)
    kreg[q] = pairs2[(size_t)b * CAP + t + q * 1024];

  u32 gv = (t < NBK) ? gcnt2[t] : 0u;
  u32 excl = scan1024_excl(gv, ws16, t);
  if (t == b) sbase_sh = excl;
  binx[t] = 0;
  if (t == 0) binx[NBIN] = 0;
  __syncthreads();
  u32 base2 = sbase_sh;
  u32 c = gcnt2[b]; if (c > CAP) c = CAP;

#pragma unroll
  for (int q = 0; q < EPB; ++q) {
    int ii = t + q * 1024;
    if (ii < (int)c) atomicAdd(&binx[(u32)(kreg[q] >> 52) & (NBIN - 1)], 1u);
  }
  __syncthreads();
  u32 bv = binx[t];
  u32 bex = scan1024_excl(bv, ws16, t);
  binx[t] = bex; bcur[t] = bex;
  if (t == NBIN - 1) binx[NBIN] = bex + bv;
  __syncthreads();
#pragma unroll
  for (int q = 0; q < EPB; ++q) {
    int ii = t + q * 1024;
    if (ii < (int)c)
      skey[atomicAdd(&bcur[(u32)(kreg[q] >> 52) & (NBIN - 1)], 1u)] = kreg[q];
  }
  __syncthreads();
  double sd = 0.0, sce = 0.0, sn = 0.0;
#pragma unroll
  for (int q = 0; q < EPB; ++q) {
    int s = t + q * 1024;
    if (s < (int)c) {
      u64 k = skey[s];
      u32 d = (u32)(k >> 52) & (NBIN - 1);
      u32 lo = binx[d], hi = binx[d + 1];
      u32 r = lo;
      for (u32 e = lo; e < hi; ++e) r += (skey[e] < k) ? 1u : 0u;
      u32 p = base2 + r;                  // final permuted position
      u32 bb = (u32)k & 0x3FFFFu;         // from-row (perm-composed)
      u32 a = p / 5u;
      float2 ta = ((const float2*)et)[a];
      float4 fb = FB[bb];
      u64 st = statT[a];
      int at = (int)(st >> 32), af = (int)fb.w;
      float ct = __uint_as_float((u32)st), cf = fb.z;
      float dx = ta.x - fb.x, dy = ta.y - fb.y;
      float dd = sqrtf(dx * dx + dy * dy);
      bool keep = !((af == at) && (cf == ct));
      float pp = 1.0f / (1.0f + dd * dd);
      float qc = fminf(fmaxf(1.0f - pp, 1e-4f), 1.0f);
      float ce = -logf(qc);
      if (keep) { sd += (double)dd; sce += (double)ce; sn += 1.0; }
    }
  }
  double vv[3] = {sd, sce, sn};
  block_sum<3, 16>(vv);
  if (t == 0) {
    sl[SL_NEGD + b] = vv[0];
    sl[SL_NEGCE + b] = vv[1];
    sl[SL_NEGN + b] = vv[2];
  }
}

// ---------------- margin + final ----------------
__global__ __launch_bounds__(256)
void k_margin(const float* __restrict__ posd, double* sl) {
  int t = threadIdx.x;
  double v[3];
  v[0] = sl[SL_POSD + t] + sl[SL_POSD + 256 + t] + sl[SL_POSD + 512 + t] + sl[SL_POSD + 768 + t];
  v[1] = sl[SL_NEGD + t] + sl[SL_NEGD + 256 + t];
  v[2] = sl[SL_NEGN + t] + sl[SL_NEGN + 256 + t];
  block_sum<3, 4>(v);
  __shared__ float sbm;
  if (t == 0) {
    float pm = (float)(v[0] / (double)B_ROWS);
    float nm = (float)(v[1] / v[2]);
    sbm = (pm + nm) * 0.5f;
  }
  __syncthreads();
  float bm = sbm;
  int i = blockIdx.x * 256 + t;
  float pd = posd[i];
  float cc = 0.f;
  if (!(__float_as_uint(pd) >> 31)) cc = fmaxf(bm - pd, 0.0f);
  double m[1] = {(double)cc};
  block_sum<1, 4>(m);
  if (t == 0) sl[SL_MAR + blockIdx.x] = m[0];
}

__global__ void k_final(const double* __restrict__ sl, float* __restrict__ out) {
  int t = threadIdx.x;
  double v[4];
  v[0] = sl[SL_POSCE + t] + sl[SL_POSCE + 256 + t] + sl[SL_POSCE + 512 + t] + sl[SL_POSCE + 768 + t];
  v[1] = sl[SL_NEGCE + t] + sl[SL_NEGCE + 256 + t];
  v[2] = sl[SL_NEGN + t] + sl[SL_NEGN + 256 + t];
  v[3] = sl[SL_MAR + t] + sl[SL_MAR + 256 + t] + sl[SL_MAR + 512 + t] + sl[SL_MAR + 768 + t];
  block_sum<4, 4>(v);
  if (t == 0) {
    float ce_mean = (float)((v[0] + v[1]) / ((double)B_ROWS + v[2]));
    float ml = (float)(v[3] / (double)B_ROWS);
    out[0] = ce_mean + ml;
  }
}

extern "C" void kernel_launch(void* const* d_in, const int* in_sizes, int n_in,
                              void* d_out, int out_size, void* d_ws, size_t ws_size,
                              hipStream_t stream) {
  const float* et  = (const float*)d_in[0];
  const float* ef  = (const float*)d_in[1];
  const float* pr  = (const float*)d_in[2];
  const float* pto = (const float*)d_in[3];
  const float* pfr = (const float*)d_in[4];
  float* out = (float*)d_out;
  if (ws_size < WS_NEEDED) return;   // diagnosable: output stays poisoned

  char* ws = (char*)d_ws;
  u64* pairs1  = (u64*)(ws + OFF_P1);
  u64* pairs2  = (u64*)(ws + OFF_P2);
  u64* statT   = (u64*)(ws + OFF_STATT);
  float4* FB   = (float4*)(ws + OFF_FB);
  float* posd  = (float*)(ws + OFF_POSD);
  u32* gcnt1   = (u32*)(ws + OFF_GC);
  u32* gcnt2   = (u32*)(ws + OFF_GC + NBK * 4);
  double* sl   = (double*)(ws + OFF_SLOTS);

  hipMemsetAsync(ws + OFF_GC, 0, 2 * NBK * 4, stream);

  // Host-side threefry split chain (jax typed key(1) = [0,1]):
  U2 key  = {0u, 1u};
  U2 key1 = tf2x32(key.a, key.b, 0u, 0u);
  U2 sk1  = tf2x32(key.a, key.b, 0u, 1u);
  U2 sk2  = tf2x32(key1.a, key1.b, 0u, 1u);

  k_pos<<<NLB + NCHUNK, 256, 0, stream>>>(et, ef, pr, pto, pfr, statT, FB, posd, sl,
                                          pairs1, gcnt1, sk1.a, sk1.b);
  k_rank1_scatter2<<<NBK, 1024, 0, stream>>>(pairs1, gcnt1, gcnt2, pairs2, sk2.a, sk2.b);
  k_rank2_loss<<<NBK, 1024, 0, stream>>>(pairs2, gcnt2, et, statT, FB, sl);
  k_margin<<<B_ROWS / 256, 256, 0, stream>>>(posd, sl);
  k_final<<<1, 256, 0, stream>>>(sl, out);
}